// Round 6
// baseline (452.281 us; speedup 1.0000x reference)
//
#include <hip/hip_runtime.h>

// Sliding-window attention, MI355X/gfx950. Round 11.
// Pipeline: convert x->bf16, convert+transpose weights -> bf16;
// 256^2 phased MFMA GEMM (qkv, bf16 out) -> V transpose -> flash windowed
// attention (R10 counted-vmcnt pipeline, unchanged) -> 256^2 GEMM with FP32
// epilogue into d_out. ws usage: 200 MB.
//
// R6: don't feed MFMA from global. R8: forced occupancy bound => spill.
// R9: gload_lds w=16 + pre-swizzled source works. R10: counted-vmcnt + raw
// s_barrier pipeline works (attn). R11: GEMMs moved from m97 128^2 (741 TF,
// 1.26e7 bank conflicts, structural ~900 ceiling) to the 256^2 template:
// BK=64, 8 waves, 128KB dbuf LDS, T2 source-swizzle (slot^(row&7)),
// 2-deep counted vmcnt(8), 4 setprio-wrapped MFMA phases per K-tile,
// STAGE(t+2) into the freed buffer after the phase-3 barrier.

typedef unsigned short u16;
typedef unsigned int u32;
typedef __attribute__((ext_vector_type(8))) short bf16x8;   // 8 x bf16 (4 VGPRs)
typedef __attribute__((ext_vector_type(4))) float f32x4;

__device__ __forceinline__ float bf2f(u16 v) {
  union { u32 u; float f; } t; t.u = ((u32)v) << 16; return t.f;
}
__device__ __forceinline__ u16 f2bf(float f) {
  union { float f; u32 u; } t; t.f = f;
  u32 u = t.u + 0x7fffu + ((t.u >> 16) & 1u);   // RNE
  return (u16)(u >> 16);
}
__device__ __forceinline__ void g2lds16(const void* g, void* l) {
  __builtin_amdgcn_global_load_lds((const __attribute__((address_space(1))) void*)g,
                                   (__attribute__((address_space(3))) void*)l,
                                   16, 0, 0);
}

// ---------------------------------------------------------------------------
// x [16384][1024] fp32 -> bf16, flat
// ---------------------------------------------------------------------------
__global__ __launch_bounds__(256) void canon_x(
    const float* __restrict__ xf, u16* __restrict__ xb) {
  size_t i = ((size_t)blockIdx.x * 256 + threadIdx.x) * 8;
  float4 a = *(const float4*)(xf + i);
  float4 b = *(const float4*)(xf + i + 4);
  u16 o[8] = { f2bf(a.x), f2bf(a.y), f2bf(a.z), f2bf(a.w),
               f2bf(b.x), f2bf(b.y), f2bf(b.z), f2bf(b.w) };
  *(bf16x8*)(xb + i) = *(bf16x8*)o;
}

// ---------------------------------------------------------------------------
// Weight transpose+convert: in [R][C] fp32 -> out [C][R] bf16
// ---------------------------------------------------------------------------
__global__ __launch_bounds__(256) void transpose_w(
    const float* __restrict__ in, u16* __restrict__ out, int R, int C) {
  __shared__ u16 tile[32][33];
  int c0 = blockIdx.x * 32, r0 = blockIdx.y * 32;
  int tx = threadIdx.x & 31, ty = threadIdx.x >> 5;
#pragma unroll
  for (int i = 0; i < 32; i += 8)
    tile[ty + i][tx] = f2bf(in[(size_t)(r0 + ty + i) * C + c0 + tx]);
  __syncthreads();
#pragma unroll
  for (int i = 0; i < 32; i += 8)
    out[(size_t)(c0 + ty + i) * R + r0 + tx] = tile[tx][ty + i];
}

// ---------------------------------------------------------------------------
// V part of qkv [16384][3072] -> Vt [bh=512][d=64][t=512]   (bf16)
// ---------------------------------------------------------------------------
__global__ __launch_bounds__(256) void transpose_v(
    const u16* __restrict__ qkv, u16* __restrict__ vt) {
  __shared__ u16 tile[32][33];
  int bh = blockIdx.z, bn = bh >> 4, h = bh & 15;
  int t0 = blockIdx.x * 32, d0 = blockIdx.y * 32;
  int tx = threadIdx.x & 31, ty = threadIdx.x >> 5;
  const u16* src = qkv + (size_t)(bn * 512) * 3072 + 2048 + h * 64;
#pragma unroll
  for (int i = 0; i < 32; i += 8)
    tile[ty + i][tx] = src[(size_t)(t0 + ty + i) * 3072 + d0 + tx];
  __syncthreads();
  u16* dst = vt + ((size_t)bh * 64 + d0) * 512 + t0;
#pragma unroll
  for (int i = 0; i < 32; i += 8)
    dst[(size_t)(ty + i) * 512 + tx] = tile[tx][ty + i];
}

// ---------------------------------------------------------------------------
// C[M,N] = A[M,K](bf16) * Bt[N,K]^T(bf16) + bias[N](fp32); OutT u16|float.
// 256^2 template: BM=BN=256, BK=64, 512 threads (2x4 waves of 128x64).
// LDS 128KB: dbuf x (A 256x64 + B 256x64) bf16, 16B slots XOR-swizzled by
// slot^(row&7) via pre-swizzled global source (linear gload_lds dest).
// Schedule per K-tile t: vmcnt(8) [2-deep] -> s_barrier -> B-frags (8 rd)
// -> 4 phases {A-frags (4 rd); setprio1; 16 MFMA; setprio0; s_barrier}
// -> STAGE(t+2) into buf[t&1] (freed at phase-3 barrier).
// Requires grid.x*grid.y % 8 == 0 for the T1 XCD swizzle (12*64, 4*64: ok).
// ---------------------------------------------------------------------------
template <typename OutT>
__global__ __launch_bounds__(512, 2) void gemm_bt_bias(
    const u16* __restrict__ A, const u16* __restrict__ Bt,
    const float* __restrict__ bias, OutT* __restrict__ C,
    int M, int N, int K) {
  __shared__ __align__(16) u16 As[2][256 * 64];
  __shared__ __align__(16) u16 Bs[2][256 * 64];
  const int tid = threadIdx.x;
  const int wave = tid >> 6, lane = tid & 63;
  const int quad = lane >> 4, l16 = lane & 15;
  const int wr = wave >> 2, wc = wave & 3;        // 2 x 4 wave grid

  // T1: XCD-contiguous logical block mapping.
  const int nbx = gridDim.x;
  const int ntot = nbx * gridDim.y;
  const int flat = blockIdx.y * nbx + blockIdx.x;
  const int swz = (flat & 7) * (ntot >> 3) + (flat >> 3);
  const int m0 = (swz / nbx) * 256, n0 = (swz % nbx) * 256;

  // staging: chunk c (16B) of a 256x64 tile: row=c>>3, slot=c&7.
  // 512 threads x 4 its cover 2048 chunks; source slot pre-swizzled.
  const int rS = tid >> 3, cS = tid & 7;

#define STAGE(KT, BUF)                                                        \
  {                                                                           \
    const int k0_ = (KT) * 64;                                                \
    _Pragma("unroll")                                                         \
    for (int it = 0; it < 4; ++it) {                                          \
      const int row = it * 64 + rS;                                           \
      const int sg = (cS ^ (row & 7)) * 8;                                    \
      g2lds16(A + (size_t)(m0 + row) * K + k0_ + sg,                          \
              &As[BUF][(size_t)(it * 512 + tid) * 8]);                        \
      g2lds16(Bt + (size_t)(n0 + row) * K + k0_ + sg,                         \
              &Bs[BUF][(size_t)(it * 512 + tid) * 8]);                        \
    }                                                                         \
  }

  f32x4 acc[8][4] = {};

  const int NT = K >> 6;                 // K-tiles of 64 (16 here)
  STAGE(0, 0);
  if (NT > 1) STAGE(1, 1);

  for (int t = 0; t < NT; ++t) {
    // 2-deep counted wait: tile t landed; tile t+1 (8 loads) stays in flight.
    if (t + 1 < NT) { asm volatile("s_waitcnt vmcnt(8)" ::: "memory"); }
    else            { asm volatile("s_waitcnt vmcnt(0)" ::: "memory"); }
    __builtin_amdgcn_s_barrier();
    __builtin_amdgcn_sched_barrier(0);

    const u16* Ab = &As[t & 1][0];
    const u16* Bb = &Bs[t & 1][0];

    // B-frags for the whole K-tile (wave's 64-col slice), 8 x ds_read_b128
    bf16x8 bfr[2][4];                    // [ks][ni]
#pragma unroll
    for (int ks = 0; ks < 2; ++ks)
#pragma unroll
      for (int ni = 0; ni < 4; ++ni) {
        int row = wc * 64 + ni * 16 + l16;
        bfr[ks][ni] = *(const bf16x8*)(Bb + row * 64 + (((ks * 4 + quad) ^ (row & 7)) * 8));
      }

    // 4 phases: mi-pair per phase, 16 MFMA each
#pragma unroll
    for (int p = 0; p < 4; ++p) {
      bf16x8 afr[2][2];                  // [mm][ks]
#pragma unroll
      for (int mm = 0; mm < 2; ++mm)
#pragma unroll
        for (int ks = 0; ks < 2; ++ks) {
          int row = wr * 128 + (p * 2 + mm) * 16 + l16;
          afr[mm][ks] = *(const bf16x8*)(Ab + row * 64 + (((ks * 4 + quad) ^ (row & 7)) * 8));
        }
      __builtin_amdgcn_s_setprio(1);
#pragma unroll
      for (int mm = 0; mm < 2; ++mm)
#pragma unroll
        for (int ni = 0; ni < 4; ++ni)
#pragma unroll
          for (int ks = 0; ks < 2; ++ks)
            acc[p * 2 + mm][ni] = __builtin_amdgcn_mfma_f32_16x16x32_bf16(
                afr[mm][ks], bfr[ks][ni], acc[p * 2 + mm][ni], 0, 0, 0);
      __builtin_amdgcn_s_setprio(0);
      __builtin_amdgcn_s_barrier();      // phase lockstep; phase-3: buf free
    }
    __builtin_amdgcn_sched_barrier(0);
    if (t + 2 < NT) STAGE(t + 2, t & 1); // refill freed buffer; lands by W(t+2)
  }
#undef STAGE

  // epilogue: C/D layout col=l16, row=quad*4+reg
#pragma unroll
  for (int ni = 0; ni < 4; ++ni) {
    int col = n0 + wc * 64 + ni * 16 + l16;
    float bv = bias[col];
#pragma unroll
    for (int mi = 0; mi < 8; ++mi) {
      int row0 = m0 + wr * 128 + mi * 16 + quad * 4;
#pragma unroll
      for (int r = 0; r < 4; ++r) {
        float v = acc[mi][ni][r] + bv;
        if constexpr (sizeof(OutT) == 2)
          C[(size_t)(row0 + r) * N + col] = f2bf(v);
        else
          C[(size_t)(row0 + r) * N + col] = v;
      }
    }
  }
}

// ---------------------------------------------------------------------------
// Windowed causal flash attention. Grid (qt=4, h=16, bn=32), 256 threads.
// R10 (verified): counted-vmcnt pipeline, raw s_barrier, no __syncthreads.
// UNCHANGED this round.
// ---------------------------------------------------------------------------
__global__ __launch_bounds__(256, 2) void attn_win(
    const u16* __restrict__ qkv, const u16* __restrict__ vt,
    u16* __restrict__ attn) {
  __shared__ __align__(16) u16 Ks[128 * 64];
  __shared__ __align__(16) u16 Vs[64 * 128];
  __shared__ __align__(16) u16 Ps[4][16 * 128];

  const int qt = blockIdx.x, h = blockIdx.y, bn = blockIdx.z;
  const int bh = bn * 16 + h;
  const int tid = threadIdx.x;
  const int wave = tid >> 6, lane = tid & 63;
  const int quad = lane >> 4, l16 = lane & 15;
  const int t0 = bn * 512 + qt * 128;

  bf16x8 aq[2][2];
#pragma unroll
  for (int mi = 0; mi < 2; ++mi)
#pragma unroll
    for (int ks = 0; ks < 2; ++ks)
      aq[mi][ks] = *(const bf16x8*)(
          qkv + (size_t)(t0 + wave * 32 + mi * 16 + l16) * 3072 + h * 64 + ks * 32 + quad * 8);

  const int rk0 = tid >> 3, ck0 = tid & 7;
  const int rv0 = tid >> 4, cv0 = tid & 15;

#define STAGE_K(JT)                                                           \
  {                                                                           \
    const int tk_ = bn * 512 + (JT) * 128;                                    \
    _Pragma("unroll")                                                         \
    for (int it = 0; it < 4; ++it) {                                          \
      int rk = it * 32 + rk0;                                                 \
      const u16* gk = qkv + (size_t)(tk_ + rk) * 3072 + 1024 + h * 64 +       \
                      ((ck0 ^ (rk & 7)) * 8);                                 \
      g2lds16(gk, Ks + (size_t)(it * 256 + wave * 64) * 8);                   \
    }                                                                         \
  }
#define STAGE_V(JT)                                                           \
  {                                                                           \
    _Pragma("unroll")                                                         \
    for (int it = 0; it < 4; ++it) {                                          \
      int rv = it * 16 + rv0;                                                 \
      const u16* gv = vt + ((size_t)bh * 64 + rv) * 512 + (JT) * 128 +        \
                      ((cv0 ^ (rv & 15)) * 8);                                \
      g2lds16(gv, Vs + (size_t)(it * 256 + wave * 64) * 8);                   \
    }                                                                         \
  }

  STAGE_K(0);
  STAGE_V(0);
  asm volatile("s_waitcnt vmcnt(4)" ::: "memory");
  __builtin_amdgcn_s_barrier();
  __builtin_amdgcn_sched_barrier(0);

  float mrun[2][4], lrun[2][4];
  f32x4 o[2][4] = {};
#pragma unroll
  for (int mi = 0; mi < 2; ++mi)
#pragma unroll
    for (int r = 0; r < 4; ++r) { mrun[mi][r] = -1e30f; lrun[mi][r] = 0.f; }

  const float cexp = 0.18033688011112042f;  // (1/sqrt(64)) * log2(e)

  u16* pw = &Ps[wave][0];

  for (int j = 0; j <= qt; ++j) {
    f32x4 s[2][8] = {};
    __builtin_amdgcn_s_setprio(1);
#pragma unroll
    for (int ks = 0; ks < 2; ++ks) {
#pragma unroll
      for (int ni = 0; ni < 8; ++ni) {
        int n = ni * 16 + l16;
        bf16x8 bk = *(const bf16x8*)(Ks + n * 64 + (((ks * 4 + quad) ^ (n & 7)) * 8));
        s[0][ni] = __builtin_amdgcn_mfma_f32_16x16x32_bf16(aq[0][ks], bk, s[0][ni], 0, 0, 0);
        s[1][ni] = __builtin_amdgcn_mfma_f32_16x16x32_bf16(aq[1][ks], bk, s[1][ni], 0, 0, 0);
      }
    }
    __builtin_amdgcn_s_setprio(0);

    __builtin_amdgcn_s_barrier();
    __builtin_amdgcn_sched_barrier(0);
    if (j < qt) STAGE_K(j + 1);

    const bool diag = (j == qt);
#pragma unroll
    for (int mi = 0; mi < 2; ++mi) {
#pragma unroll
      for (int r = 0; r < 4; ++r) {
        int m = wave * 32 + mi * 16 + quad * 4 + r;
        float rmax = -1e30f;
#pragma unroll
        for (int ni = 0; ni < 8; ++ni) {
          float v = s[mi][ni][r] * cexp;
          if (diag && (ni * 16 + l16 > m)) v = -1e30f;
          s[mi][ni][r] = v;
          rmax = fmaxf(rmax, v);
        }
        rmax = fmaxf(rmax, __shfl_xor(rmax, 1));
        rmax = fmaxf(rmax, __shfl_xor(rmax, 2));
        rmax = fmaxf(rmax, __shfl_xor(rmax, 4));
        rmax = fmaxf(rmax, __shfl_xor(rmax, 8));
        float mnew = fmaxf(mrun[mi][r], rmax);
        float alpha = exp2f(mrun[mi][r] - mnew);
        mrun[mi][r] = mnew;
        float rsum = 0.f;
#pragma unroll
        for (int ni = 0; ni < 8; ++ni) {
          float pv = exp2f(s[mi][ni][r] - mnew);
          s[mi][ni][r] = pv;
          rsum += pv;
        }
        rsum += __shfl_xor(rsum, 1);
        rsum += __shfl_xor(rsum, 2);
        rsum += __shfl_xor(rsum, 4);
        rsum += __shfl_xor(rsum, 8);
        lrun[mi][r] = lrun[mi][r] * alpha + rsum;
#pragma unroll
        for (int di = 0; di < 4; ++di) o[mi][di][r] *= alpha;
      }
    }

    if (j < qt) { asm volatile("s_waitcnt vmcnt(4)" ::: "memory"); }
    else        { asm volatile("s_waitcnt vmcnt(0)" ::: "memory"); }
    __builtin_amdgcn_s_barrier();
    __builtin_amdgcn_sched_barrier(0);

#pragma unroll
    for (int mi = 0; mi < 2; ++mi) {
#pragma unroll
      for (int ni = 0; ni < 8; ++ni)
#pragma unroll
        for (int r = 0; r < 4; ++r) {
          int row = quad * 4 + r;
          int col = ni * 16 + l16;
          int phys = (col >> 3) ^ row;
          pw[row * 128 + phys * 8 + (col & 7)] = f2bf(s[mi][ni][r]);
        }

      __builtin_amdgcn_s_setprio(1);
#pragma unroll
      for (int ksv = 0; ksv < 4; ++ksv) {
        bf16x8 ap = *(const bf16x8*)(pw + l16 * 128 + (((ksv * 4 + quad) ^ l16) * 8));
#pragma unroll
        for (int di = 0; di < 4; ++di) {
          int n = di * 16 + l16;
          bf16x8 bv = *(const bf16x8*)(Vs + n * 128 + (((ksv * 4 + quad) ^ (n & 15)) * 8));
          o[mi][di] = __builtin_amdgcn_mfma_f32_16x16x32_bf16(ap, bv, o[mi][di], 0, 0, 0);
        }
      }
      __builtin_amdgcn_s_setprio(0);
    }

    asm volatile("s_waitcnt vmcnt(0)" ::: "memory");
    __builtin_amdgcn_s_barrier();
    __builtin_amdgcn_sched_barrier(0);
    if (j < qt) STAGE_V(j + 1);
  }
#undef STAGE_K
#undef STAGE_V

#pragma unroll
  for (int mi = 0; mi < 2; ++mi)
#pragma unroll
    for (int r = 0; r < 4; ++r) {
      float inv = 1.0f / lrun[mi][r];
      int trow = t0 + wave * 32 + mi * 16 + quad * 4 + r;
#pragma unroll
      for (int di = 0; di < 4; ++di)
        attn[(size_t)trow * 1024 + h * 64 + di * 16 + l16] = f2bf(o[mi][di][r] * inv);
    }
}

// ---------------------------------------------------------------------------
extern "C" void kernel_launch(void* const* d_in, const int* in_sizes, int n_in,
                              void* d_out, int out_size, void* d_ws, size_t ws_size,
                              hipStream_t stream) {
  (void)in_sizes; (void)n_in; (void)out_size; (void)ws_size;
  const float* x     = (const float*)d_in[0];   // [16384][1024] fp32
  const float* w_qkv = (const float*)d_in[1];   // [1024][3072] fp32
  const float* b_qkv = (const float*)d_in[2];   // [3072] fp32
  const float* w_o   = (const float*)d_in[3];   // [1024][1024] fp32
  const float* b_o   = (const float*)d_in[4];   // [1024] fp32
  float* out = (float*)d_out;                   // [16384][1024] fp32

  char* ws = (char*)d_ws;
  u16* qkv   = (u16*)(ws + 0);            // 96 MB
  u16* vtb   = (u16*)(ws + 100663296);    // 32 MB
  u16* attnb = (u16*)(ws + 134217728);    // 32 MB
  u16* xb    = (u16*)(ws + 167772160);    // 32 MB
  u16* wqkvT = (u16*)(ws + 201326592);    // 6 MB
  u16* woT   = (u16*)(ws + 207618048);    // 2 MB  (total 200 MB)

  canon_x<<<8192, 256, 0, stream>>>(x, xb);
  transpose_w<<<dim3(96, 32), 256, 0, stream>>>(w_qkv, wqkvT, 1024, 3072);
  transpose_w<<<dim3(32, 32), 256, 0, stream>>>(w_o, woT, 1024, 1024);

  gemm_bt_bias<u16><<<dim3(12, 64), 512, 0, stream>>>(
      xb, wqkvT, b_qkv, qkv, 16384, 3072, 1024);
  transpose_v<<<dim3(16, 2, 512), 256, 0, stream>>>(qkv, vtb);
  attn_win<<<dim3(4, 16, 32), 256, 0, stream>>>(qkv, vtb, attnb);
  gemm_bt_bias<float><<<dim3(4, 64), 512, 0, stream>>>(
      attnb, woT, b_o, out, 16384, 1024, 1024);
}